// Round 2
// baseline (429.003 us; speedup 1.0000x reference)
//
#include <hip/hip_runtime.h>
#include <hip/hip_bf16.h>

#define NN 8192
#define KF 512
#define FF 64
#define GAT_ALPHA 0.2f
#define MSHIFT 20.0f          // safe upper bound on max_j e2[j] (pre-scale)
#define LOG2E 1.44269504f

#define JSPLIT 16             // grid = 128 row-groups x 16 = 2048 blocks
#define JW (NN / JSPLIT)      // 512 j per block
#define KSTEPS (JW / 32)      // 16 k-steps of 32

#define EXP2F(x) __builtin_amdgcn_exp2f(x)

typedef __attribute__((ext_vector_type(8))) __bf16 bf16x8;
typedef __attribute__((ext_vector_type(4))) float f32x4;
typedef __attribute__((ext_vector_type(4))) int i32x4;

// RNE fp32->bf16 pair pack, pure bit ops. Returns (bf16(hi)<<16)|bf16(lo).
__device__ __forceinline__ unsigned pack_bf16_rne(float hi, float lo) {
    unsigned uh = __float_as_uint(hi);
    unsigned ul = __float_as_uint(lo);
    uh = uh + 0x7FFFu + ((uh >> 16) & 1u);
    ul = ul + 0x7FFFu + ((ul >> 16) & 1u);
    return (uh & 0xFFFF0000u) | (ul >> 16);
}

// ---------------------------------------------------------------------------
// Kernel A: h = x@W (fp32), e1/e2 = (h@a1, h@a2) * log2(e),
//           ht = h^T bf16 [64][8192]. 256 blocks x 256 thr, 32 rows/block.
// (unchanged this round — isolate the gat_attn rewrite)
// ---------------------------------------------------------------------------
__global__ __launch_bounds__(256) void gat_linear(
    const float* __restrict__ x, const float* __restrict__ W,
    const float* __restrict__ av, __hip_bfloat16* __restrict__ ht,
    float* __restrict__ e1, float* __restrict__ e2)
{
    __shared__ float xs[32][33];
    __shared__ float Ws[32][64];
    __shared__ float ep[2][32][17];

    const int t  = threadIdx.x;
    const int fq = t & 15;
    const int rq = t >> 4;
    const int i0 = blockIdx.x * 32;

    const int kl = t & 31, r0 = t >> 5;
    const int fw = t & 63, kq = t >> 6;

    float acc[2][4] = {};

    for (int kt = 0; kt < KF; kt += 32) {
        #pragma unroll
        for (int m = 0; m < 4; ++m)
            xs[kl][r0 + 8 * m] = x[(size_t)(i0 + r0 + 8 * m) * KF + kt + kl];
        #pragma unroll
        for (int m = 0; m < 8; ++m)
            Ws[kq + 4 * m][fw] = W[(size_t)(kt + kq + 4 * m) * FF + fw];
        __syncthreads();
        #pragma unroll
        for (int kk = 0; kk < 32; ++kk) {
            float x0 = xs[kk][rq * 2];
            float x1 = xs[kk][rq * 2 + 1];
            f32x4 wv = *(const f32x4*)&Ws[kk][fq * 4];
            #pragma unroll
            for (int v = 0; v < 4; ++v) {
                acc[0][v] += x0 * wv[v];
                acc[1][v] += x1 * wv[v];
            }
        }
        __syncthreads();
    }

    #pragma unroll
    for (int v = 0; v < 4; ++v) {
        int f = fq * 4 + v;
        unsigned w = pack_bf16_rne(acc[1][v], acc[0][v]);
        *(unsigned*)&ht[(size_t)f * NN + i0 + rq * 2] = w;
    }

    f32x4 a1v = *(const f32x4*)&av[fq * 4];
    f32x4 a2v = *(const f32x4*)&av[64 + fq * 4];
    #pragma unroll
    for (int u = 0; u < 2; ++u) {
        float s1 = 0.f, s2 = 0.f;
        #pragma unroll
        for (int v = 0; v < 4; ++v) {
            s1 += acc[u][v] * a1v[v];
            s2 += acc[u][v] * a2v[v];
        }
        ep[0][rq * 2 + u][fq] = s1;
        ep[1][rq * 2 + u][fq] = s2;
    }
    __syncthreads();
    if (t < 32) {
        float s1 = 0.f, s2 = 0.f;
        #pragma unroll
        for (int q = 0; q < 16; ++q) { s1 += ep[0][t][q]; s2 += ep[1][t][q]; }
        e1[i0 + t] = s1 * LOG2E;
        e2[i0 + t] = s2 * LOG2E;
    }
}

// ---------------------------------------------------------------------------
// Kernel B: zero-LDS streaming. Block = 64 rows x 512 j, 4 waves.
// No staging phase, no barrier, LDS = 0 -> __launch_bounds__(256,4) gives
// 16 waves/CU (was 8, LDS-capped). Per step each lane reads its OWN slice:
//   adj[row][j..j+8]   : 2x dwordx4, 4 quads cover one full 128B line -> the
//                        268MB read-once HBM stream (2-step prefetch)
//   e2[j..j+8]         : 2x dwordx4, L1-resident (32KB total)
//   ht[f][j..j+8] x4   : 4x dwordx4, L2-resident (1MB total), exact same
//                        B-fragment indices the old LDS read produced
// Loop is pure VMEM + VALU + MFMA; compiler pipelines via vmcnt.
// ---------------------------------------------------------------------------
__global__ __launch_bounds__(256, 4) void gat_attn(
    const int* __restrict__ adj, const __hip_bfloat16* __restrict__ ht,
    const float* __restrict__ e1, const float* __restrict__ e2,
    float* __restrict__ accs, float* __restrict__ lsums)
{
    const int t     = threadIdx.x;
    const int lane  = t & 63;
    const int wv    = t >> 6;
    const int n16   = lane & 15;
    const int quad  = lane >> 4;
    const int split = blockIdx.x & (JSPLIT - 1);
    const int i0    = (blockIdx.x >> 4) * 64 + wv * 16;  // wave row base
    const int j0    = split * JW;
    const int row   = i0 + n16;                           // global query row

    const float e1L = e1[row];
    float ms = e1L + MSHIFT * LOG2E;
    const float miL = ms > 0.f ? ms : GAT_ALPHA * ms;
    const float c0  = e1L - miL;                 // t0 = e2 + c0
    const float c1  = GAT_ALPHA * e1L - miL;     // t1 = fma(alpha, e2, c1)

    const int jb = j0 + quad * 8;                // lane's j base, stride 32/step
    const int*            __restrict__ ap  = adj + (size_t)row * NN + jb;
    const float*          __restrict__ e2p = e2 + jb;
    const __hip_bfloat16* __restrict__ hb  = ht + (size_t)n16 * NN + jb;

    f32x4 dacc0 = {0.f,0.f,0.f,0.f}, dacc1 = {0.f,0.f,0.f,0.f};
    f32x4 dacc2 = {0.f,0.f,0.f,0.f}, dacc3 = {0.f,0.f,0.f,0.f};
    f32x4 dl    = {0.f,0.f,0.f,0.f};

    const i32x4 ones_i = {0x3F803F80, 0x3F803F80, 0x3F803F80, 0x3F803F80};
    const bf16x8 ones  = __builtin_bit_cast(bf16x8, ones_i);

    // --- software pipeline: adj (HBM) 2 deep; e2/ht (cache-hit) 1 deep ---
    i32x4 aN0 = *(const i32x4*)(ap);
    i32x4 aN1 = *(const i32x4*)(ap + 4);
    i32x4 aM0 = *(const i32x4*)(ap + 32);
    i32x4 aM1 = *(const i32x4*)(ap + 36);
    f32x4  e0 = *(const f32x4*)(e2p);
    f32x4  ev = *(const f32x4*)(e2p + 4);
    bf16x8 b0 = *(const bf16x8*)(hb);
    bf16x8 b1 = *(const bf16x8*)(hb + (size_t)16 * NN);
    bf16x8 b2 = *(const bf16x8*)(hb + (size_t)32 * NN);
    bf16x8 b3 = *(const bf16x8*)(hb + (size_t)48 * NN);

    for (int st = 0; st < KSTEPS; ++st) {
        const i32x4  ca0 = aN0, ca1 = aN1;
        const f32x4  ce0 = e0,  cev = ev;
        const bf16x8 cb0 = b0, cb1 = b1, cb2 = b2, cb3 = b3;
        aN0 = aM0; aN1 = aM1;
        if (st + 2 < KSTEPS) {
            const int o = (st + 2) * 32;
            aM0 = *(const i32x4*)(ap + o);
            aM1 = *(const i32x4*)(ap + o + 4);
        }
        if (st + 1 < KSTEPS) {
            const int o = (st + 1) * 32;
            e0 = *(const f32x4*)(e2p + o);
            ev = *(const f32x4*)(e2p + o + 4);
            b0 = *(const bf16x8*)(hb + o);
            b1 = *(const bf16x8*)(hb + (size_t)16 * NN + o);
            b2 = *(const bf16x8*)(hb + (size_t)32 * NN + o);
            b3 = *(const bf16x8*)(hb + (size_t)48 * NN + o);
        }

#define PJ(eval, an)                                                           \
        ( (an) > 0                                                             \
            ? EXP2F(fmaxf(c0 + (eval), __builtin_fmaf(GAT_ALPHA, (eval), c1))) \
            : 0.f )
        float p0 = PJ(ce0.x, ca0.x);
        float p1 = PJ(ce0.y, ca0.y);
        float p2 = PJ(ce0.z, ca0.z);
        float p3 = PJ(ce0.w, ca0.w);
        float p4 = PJ(cev.x, ca1.x);
        float p5 = PJ(cev.y, ca1.y);
        float p6 = PJ(cev.z, ca1.z);
        float p7 = PJ(cev.w, ca1.w);
#undef PJ
        i32x4 iv;
        iv.x = (int)pack_bf16_rne(p1, p0);
        iv.y = (int)pack_bf16_rne(p3, p2);
        iv.z = (int)pack_bf16_rne(p5, p4);
        iv.w = (int)pack_bf16_rne(p7, p6);
        bf16x8 af = __builtin_bit_cast(bf16x8, iv);

        dacc0 = __builtin_amdgcn_mfma_f32_16x16x32_bf16(af, cb0, dacc0, 0, 0, 0);
        dacc1 = __builtin_amdgcn_mfma_f32_16x16x32_bf16(af, cb1, dacc1, 0, 0, 0);
        dacc2 = __builtin_amdgcn_mfma_f32_16x16x32_bf16(af, cb2, dacc2, 0, 0, 0);
        dacc3 = __builtin_amdgcn_mfma_f32_16x16x32_bf16(af, cb3, dacc3, 0, 0, 0);
        dl    = __builtin_amdgcn_mfma_f32_16x16x32_bf16(af, ones, dl, 0, 0, 0);
    }

    // dl D-tile: every column holds the row-sum; lanes n16==0 cover all 16 rows
    if (n16 == 0) {
        lsums[(size_t)split * NN + i0 + quad * 4 + 0] = dl.x;
        lsums[(size_t)split * NN + i0 + quad * 4 + 1] = dl.y;
        lsums[(size_t)split * NN + i0 + quad * 4 + 2] = dl.z;
        lsums[(size_t)split * NN + i0 + quad * 4 + 3] = dl.w;
    }

    // D layout: col = lane&15 (feature), row = quad*4 + reg (m89-verified)
    float* ab = accs + (size_t)split * NN * FF + (size_t)(i0 + quad * 4) * FF + n16;
#define STORE4(dv, ftofs)                                                      \
    ab[0 * FF + (ftofs)] = (dv).x;                                             \
    ab[1 * FF + (ftofs)] = (dv).y;                                             \
    ab[2 * FF + (ftofs)] = (dv).z;                                             \
    ab[3 * FF + (ftofs)] = (dv).w;
    STORE4(dacc0, 0)
    STORE4(dacc1, 16)
    STORE4(dacc2, 32)
    STORE4(dacc3, 48)
#undef STORE4
}

// ---------------------------------------------------------------------------
// Epilogue: out = elu( (sum_s accs[s]) / (sum_s lsums[s]) )  (unchanged)
// ---------------------------------------------------------------------------
__global__ __launch_bounds__(256) void gat_epilogue(
    const float* __restrict__ accs, const float* __restrict__ lsums,
    float* __restrict__ out)
{
    const int idx = (blockIdx.x * 256 + threadIdx.x) * 4;  // 4 consecutive f, same row
    const int row = idx >> 6;

    float l = 0.f;
    #pragma unroll
    for (int s = 0; s < JSPLIT; ++s) l += lsums[(size_t)s * NN + row];

    f32x4 a = {0.f, 0.f, 0.f, 0.f};
    #pragma unroll
    for (int s = 0; s < JSPLIT; ++s) {
        f32x4 v = *(const f32x4*)(accs + (size_t)s * NN * FF + idx);
        a.x += v.x; a.y += v.y; a.z += v.z; a.w += v.w;
    }

    const float li = 1.f / l;
    f32x4 o;
    o.x = a.x * li; o.y = a.y * li; o.z = a.z * li; o.w = a.w * li;
    o.x = o.x > 0.f ? o.x : __expf(o.x) - 1.f;
    o.y = o.y > 0.f ? o.y : __expf(o.y) - 1.f;
    o.z = o.z > 0.f ? o.z : __expf(o.z) - 1.f;
    o.w = o.w > 0.f ? o.w : __expf(o.w) - 1.f;
    *(f32x4*)(out + idx) = o;
}

extern "C" void kernel_launch(void* const* d_in, const int* in_sizes, int n_in,
                              void* d_out, int out_size, void* d_ws, size_t ws_size,
                              hipStream_t stream) {
    const float* x   = (const float*)d_in[0];
    const int*   adj = (const int*)d_in[1];
    const float* W   = (const float*)d_in[2];
    const float* av  = (const float*)d_in[3];
    float* out = (float*)d_out;

    // ws: ht bf16[64*8192] (1MB) | e1 f32[8192] | e2 f32[8192]
    //     | accs f32[16][8192*64] (32MB) | lsums f32[16][8192] (512KB)
    char* wsb = (char*)d_ws;
    __hip_bfloat16* ht = (__hip_bfloat16*)wsb;
    float* e1    = (float*)(wsb + (1 << 20));
    float* e2    = e1 + NN;
    float* accs  = e2 + NN;
    float* lsums = accs + (size_t)JSPLIT * NN * FF;

    gat_linear<<<256, 256, 0, stream>>>(x, W, av, ht, e1, e2);
    gat_attn<<<(NN / 64) * JSPLIT, 256, 0, stream>>>(adj, ht, e1, e2, accs, lsums);
    gat_epilogue<<<NN * FF / 1024, 256, 0, stream>>>(accs, lsums, out);
}

// Round 3
// 408.674 us; speedup vs baseline: 1.0497x; 1.0497x over previous
//
#include <hip/hip_runtime.h>
#include <hip/hip_bf16.h>

#define NN 8192
#define KF 512
#define FF 64
#define GAT_ALPHA 0.2f
#define MSHIFT 20.0f          // safe upper bound on max_j e2[j] (pre-scale)
#define LOG2E 1.44269504f

#define JSPLIT 32             // grid = 128 row-groups x 32 = 4096 blocks
#define JSHIFT 5
#define JW (NN / JSPLIT)      // 256 j per block
#define KSTEPS (JW / 32)      // 8 k-steps of 32

#define HTS 264               // hs row stride (bf16): 132 dwords, %32=4 -> 2-way (free)

#define EXP2F(x) __builtin_amdgcn_exp2f(x)

typedef __attribute__((ext_vector_type(8))) __bf16 bf16x8;
typedef __attribute__((ext_vector_type(4))) float f32x4;
typedef __attribute__((ext_vector_type(4))) int i32x4;

// RNE fp32->bf16 pair pack, pure bit ops. Returns (bf16(hi)<<16)|bf16(lo).
__device__ __forceinline__ unsigned pack_bf16_rne(float hi, float lo) {
    unsigned uh = __float_as_uint(hi);
    unsigned ul = __float_as_uint(lo);
    uh = uh + 0x7FFFu + ((uh >> 16) & 1u);
    ul = ul + 0x7FFFu + ((ul >> 16) & 1u);
    return (uh & 0xFFFF0000u) | (ul >> 16);
}

// ---------------------------------------------------------------------------
// Kernel A: h = x@W (fp32), e1/e2 = (h@a1, h@a2) * log2(e),
//           ht = h^T bf16 [64][8192]. 256 blocks x 256 thr, 32 rows/block.
// (unchanged — proven)
// ---------------------------------------------------------------------------
__global__ __launch_bounds__(256) void gat_linear(
    const float* __restrict__ x, const float* __restrict__ W,
    const float* __restrict__ av, __hip_bfloat16* __restrict__ ht,
    float* __restrict__ e1, float* __restrict__ e2)
{
    __shared__ float xs[32][33];
    __shared__ float Ws[32][64];
    __shared__ float ep[2][32][17];

    const int t  = threadIdx.x;
    const int fq = t & 15;
    const int rq = t >> 4;
    const int i0 = blockIdx.x * 32;

    const int kl = t & 31, r0 = t >> 5;
    const int fw = t & 63, kq = t >> 6;

    float acc[2][4] = {};

    for (int kt = 0; kt < KF; kt += 32) {
        #pragma unroll
        for (int m = 0; m < 4; ++m)
            xs[kl][r0 + 8 * m] = x[(size_t)(i0 + r0 + 8 * m) * KF + kt + kl];
        #pragma unroll
        for (int m = 0; m < 8; ++m)
            Ws[kq + 4 * m][fw] = W[(size_t)(kt + kq + 4 * m) * FF + fw];
        __syncthreads();
        #pragma unroll
        for (int kk = 0; kk < 32; ++kk) {
            float x0 = xs[kk][rq * 2];
            float x1 = xs[kk][rq * 2 + 1];
            f32x4 wv = *(const f32x4*)&Ws[kk][fq * 4];
            #pragma unroll
            for (int v = 0; v < 4; ++v) {
                acc[0][v] += x0 * wv[v];
                acc[1][v] += x1 * wv[v];
            }
        }
        __syncthreads();
    }

    #pragma unroll
    for (int v = 0; v < 4; ++v) {
        int f = fq * 4 + v;
        unsigned w = pack_bf16_rne(acc[1][v], acc[0][v]);
        *(unsigned*)&ht[(size_t)f * NN + i0 + rq * 2] = w;
    }

    f32x4 a1v = *(const f32x4*)&av[fq * 4];
    f32x4 a2v = *(const f32x4*)&av[64 + fq * 4];
    #pragma unroll
    for (int u = 0; u < 2; ++u) {
        float s1 = 0.f, s2 = 0.f;
        #pragma unroll
        for (int v = 0; v < 4; ++v) {
            s1 += acc[u][v] * a1v[v];
            s2 += acc[u][v] * a2v[v];
        }
        ep[0][rq * 2 + u][fq] = s1;
        ep[1][rq * 2 + u][fq] = s2;
    }
    __syncthreads();
    if (t < 32) {
        float s1 = 0.f, s2 = 0.f;
        #pragma unroll
        for (int q = 0; q < 16; ++q) { s1 += ep[0][t][q]; s2 += ep[1][t][q]; }
        e1[i0 + t] = s1 * LOG2E;
        e2[i0 + t] = s2 * LOG2E;
    }
}

// ---------------------------------------------------------------------------
// Kernel B: LDS-resident hot loop (proven R0 structure), JSPLIT 16->32.
// Block = 64 rows x 256 j. LDS = 36.9KB (was 72.9KB) -> 4 blocks/CU
// (was 2): staging of one block overlaps compute of three others, keeping
// the 268MB adj HBM stream continuously fed.
// Prologue: ht slice 32KB -> hs[64][264]; e2 slice 1KB; adj slice 64KB
// (coalesced, read once grid-wide) -> 2.1KB bitmask. One barrier.
// Loop: 8 steps, ONLY ds_read + VALU + MFMA, 1-step register prefetch.
// ---------------------------------------------------------------------------
__global__ __launch_bounds__(256, 4) void gat_attn(
    const int* __restrict__ adj, const __hip_bfloat16* __restrict__ ht,
    const float* __restrict__ e1, const float* __restrict__ e2,
    float* __restrict__ accs, float* __restrict__ lsums)
{
    __shared__ __hip_bfloat16 hs[64 * HTS];            // 33792 B
    __shared__ float e2s[JW];                          // 1024 B
    __shared__ unsigned char msk[KSTEPS * 4 * 68];     // 2176 B  [st][quad][row(+pad)]

    const int t     = threadIdx.x;
    const int lane  = t & 63;
    const int wv    = t >> 6;
    const int n16   = lane & 15;
    const int quad  = lane >> 4;
    const int split = blockIdx.x & (JSPLIT - 1);
    const int i0b   = (blockIdx.x >> JSHIFT) * 64;     // block row base
    const int i0    = i0b + wv * 16;                   // wave row base
    const int j0    = split * JW;
    const int rowl  = wv * 16 + n16;                   // block-local row
    const int row   = i0 + n16;                        // global row

    // ---- stage ht slice: [64][256] bf16, coalesced ----
    #pragma unroll
    for (int k = 0; k < 8; ++k) {
        int g  = t + k * 256;          // 2048 chunks of 8 bf16
        int f  = g >> 5;
        int jl = (g & 31) * 8;
        *(bf16x8*)&hs[f * HTS + jl] =
            *(const bf16x8*)&ht[(size_t)f * NN + j0 + jl];
    }
    // ---- stage e2 slice ----
    if (t < JW / 4)
        *(float4*)&e2s[t * 4] = *(const float4*)&e2[j0 + t * 4];

    // ---- adj slice -> LDS bitmask (adj read once grid-wide) ----
    {
        const int st = t & 7;
        #pragma unroll
        for (int rep = 0; rep < 2; ++rep) {
            const int r = rep * 32 + (t >> 3);         // block-local row 0..63
            const int* ap = adj + (size_t)(i0b + r) * NN + j0 + st * 32;
            unsigned w = 0;
            #pragma unroll
            for (int k = 0; k < 8; ++k) {
                int4 v = *(const int4*)(ap + k * 4);
                unsigned nib =  (unsigned)(v.x > 0)
                             | ((unsigned)(v.y > 0) << 1)
                             | ((unsigned)(v.z > 0) << 2)
                             | ((unsigned)(v.w > 0) << 3);
                w |= nib << (k * 4);
            }
            msk[(st * 4 + 0) * 68 + r] = (unsigned char)(w       & 0xFF);
            msk[(st * 4 + 1) * 68 + r] = (unsigned char)((w >> 8)  & 0xFF);
            msk[(st * 4 + 2) * 68 + r] = (unsigned char)((w >> 16) & 0xFF);
            msk[(st * 4 + 3) * 68 + r] = (unsigned char)((w >> 24) & 0xFF);
        }
    }
    __syncthreads();

    const float e1L = e1[row];
    float ms = e1L + MSHIFT * LOG2E;
    const float miL = ms > 0.f ? ms : GAT_ALPHA * ms;
    const float c0  = e1L - miL;                 // t0 = e2 + c0
    const float c1  = GAT_ALPHA * e1L - miL;     // t1 = fma(alpha, e2, c1)

    const __hip_bfloat16* hp = hs + n16 * HTS + quad * 8;  // B rows n16,+16,+32,+48
    const float* ep0 = e2s + quad * 8;

    f32x4 dacc0 = {0.f,0.f,0.f,0.f}, dacc1 = {0.f,0.f,0.f,0.f};
    f32x4 dacc2 = {0.f,0.f,0.f,0.f}, dacc3 = {0.f,0.f,0.f,0.f};
    f32x4 dl    = {0.f,0.f,0.f,0.f};

    const i32x4 ones_i = {0x3F803F80, 0x3F803F80, 0x3F803F80, 0x3F803F80};
    const bf16x8 ones  = __builtin_bit_cast(bf16x8, ones_i);

    // prefetch step 0
    unsigned mb = msk[(0 * 4 + quad) * 68 + rowl];
    f32x4  e0 = *(const f32x4*)(ep0);
    f32x4  ev = *(const f32x4*)(ep0 + 4);
    bf16x8 b0 = *(const bf16x8*)(hp);
    bf16x8 b1 = *(const bf16x8*)(hp + 16 * HTS);
    bf16x8 b2 = *(const bf16x8*)(hp + 32 * HTS);
    bf16x8 b3 = *(const bf16x8*)(hp + 48 * HTS);

    for (int st = 0; st < KSTEPS; ++st) {
        const unsigned mc = mb;
        const f32x4  ce0 = e0, cev = ev;
        const bf16x8 cb0 = b0, cb1 = b1, cb2 = b2, cb3 = b3;
        if (st + 1 < KSTEPS) {
            mb = msk[((st + 1) * 4 + quad) * 68 + rowl];
            e0 = *(const f32x4*)(ep0 + (st + 1) * 32);
            ev = *(const f32x4*)(ep0 + (st + 1) * 32 + 4);
            b0 = *(const bf16x8*)(hp + (st + 1) * 32);
            b1 = *(const bf16x8*)(hp + 16 * HTS + (st + 1) * 32);
            b2 = *(const bf16x8*)(hp + 32 * HTS + (st + 1) * 32);
            b3 = *(const bf16x8*)(hp + 48 * HTS + (st + 1) * 32);
        }

#define PJ(eval, bit)                                                          \
        ( ((mc >> (bit)) & 1u)                                                 \
            ? EXP2F(fmaxf(c0 + (eval), __builtin_fmaf(GAT_ALPHA, (eval), c1))) \
            : 0.f )
        float p0 = PJ(ce0.x, 0);
        float p1 = PJ(ce0.y, 1);
        float p2 = PJ(ce0.z, 2);
        float p3 = PJ(ce0.w, 3);
        float p4 = PJ(cev.x, 4);
        float p5 = PJ(cev.y, 5);
        float p6 = PJ(cev.z, 6);
        float p7 = PJ(cev.w, 7);
#undef PJ
        i32x4 iv;
        iv.x = (int)pack_bf16_rne(p1, p0);
        iv.y = (int)pack_bf16_rne(p3, p2);
        iv.z = (int)pack_bf16_rne(p5, p4);
        iv.w = (int)pack_bf16_rne(p7, p6);
        bf16x8 af = __builtin_bit_cast(bf16x8, iv);

        dacc0 = __builtin_amdgcn_mfma_f32_16x16x32_bf16(af, cb0, dacc0, 0, 0, 0);
        dacc1 = __builtin_amdgcn_mfma_f32_16x16x32_bf16(af, cb1, dacc1, 0, 0, 0);
        dacc2 = __builtin_amdgcn_mfma_f32_16x16x32_bf16(af, cb2, dacc2, 0, 0, 0);
        dacc3 = __builtin_amdgcn_mfma_f32_16x16x32_bf16(af, cb3, dacc3, 0, 0, 0);
        dl    = __builtin_amdgcn_mfma_f32_16x16x32_bf16(af, ones, dl, 0, 0, 0);
    }

    // dl D-tile: every column holds the row-sum; lanes n16==0 cover all 16 rows
    if (n16 == 0) {
        lsums[(size_t)split * NN + i0 + quad * 4 + 0] = dl.x;
        lsums[(size_t)split * NN + i0 + quad * 4 + 1] = dl.y;
        lsums[(size_t)split * NN + i0 + quad * 4 + 2] = dl.z;
        lsums[(size_t)split * NN + i0 + quad * 4 + 3] = dl.w;
    }

    // D layout: col = lane&15 (feature), row = quad*4 + reg (m89-verified)
    float* ab = accs + (size_t)split * NN * FF + (size_t)(i0 + quad * 4) * FF + n16;
#define STORE4(dv, ftofs)                                                      \
    ab[0 * FF + (ftofs)] = (dv).x;                                             \
    ab[1 * FF + (ftofs)] = (dv).y;                                             \
    ab[2 * FF + (ftofs)] = (dv).z;                                             \
    ab[3 * FF + (ftofs)] = (dv).w;
    STORE4(dacc0, 0)
    STORE4(dacc1, 16)
    STORE4(dacc2, 32)
    STORE4(dacc3, 48)
#undef STORE4
}

// ---------------------------------------------------------------------------
// Epilogue: out = elu( (sum_s accs[s]) / (sum_s lsums[s]) )
// ---------------------------------------------------------------------------
__global__ __launch_bounds__(256) void gat_epilogue(
    const float* __restrict__ accs, const float* __restrict__ lsums,
    float* __restrict__ out)
{
    const int idx = (blockIdx.x * 256 + threadIdx.x) * 4;  // 4 consecutive f, same row
    const int row = idx >> 6;

    float l = 0.f;
    #pragma unroll
    for (int s = 0; s < JSPLIT; ++s) l += lsums[(size_t)s * NN + row];

    f32x4 a = {0.f, 0.f, 0.f, 0.f};
    #pragma unroll
    for (int s = 0; s < JSPLIT; ++s) {
        f32x4 v = *(const f32x4*)(accs + (size_t)s * NN * FF + idx);
        a.x += v.x; a.y += v.y; a.z += v.z; a.w += v.w;
    }

    const float li = 1.f / l;
    f32x4 o;
    o.x = a.x * li; o.y = a.y * li; o.z = a.z * li; o.w = a.w * li;
    o.x = o.x > 0.f ? o.x : __expf(o.x) - 1.f;
    o.y = o.y > 0.f ? o.y : __expf(o.y) - 1.f;
    o.z = o.z > 0.f ? o.z : __expf(o.z) - 1.f;
    o.w = o.w > 0.f ? o.w : __expf(o.w) - 1.f;
    *(f32x4*)(out + idx) = o;
}

extern "C" void kernel_launch(void* const* d_in, const int* in_sizes, int n_in,
                              void* d_out, int out_size, void* d_ws, size_t ws_size,
                              hipStream_t stream) {
    const float* x   = (const float*)d_in[0];
    const int*   adj = (const int*)d_in[1];
    const float* W   = (const float*)d_in[2];
    const float* av  = (const float*)d_in[3];
    float* out = (float*)d_out;

    // ws: ht bf16[64*8192] (1MB) | e1 f32[8192] | e2 f32[8192]
    //     | accs f32[32][8192*64] (64MB) | lsums f32[32][8192] (1MB)
    char* wsb = (char*)d_ws;
    __hip_bfloat16* ht = (__hip_bfloat16*)wsb;
    float* e1    = (float*)(wsb + (1 << 20));
    float* e2    = e1 + NN;
    float* accs  = e2 + NN;
    float* lsums = accs + (size_t)JSPLIT * NN * FF;

    gat_linear<<<256, 256, 0, stream>>>(x, W, av, ht, e1, e2);
    gat_attn<<<(NN / 64) * JSPLIT, 256, 0, stream>>>(adj, ht, e1, e2, accs, lsums);
    gat_epilogue<<<NN * FF / 1024, 256, 0, stream>>>(accs, lsums, out);
}

// Round 4
// 399.992 us; speedup vs baseline: 1.0725x; 1.0217x over previous
//
#include <hip/hip_runtime.h>
#include <hip/hip_bf16.h>

#define NN 8192
#define KF 512
#define FF 64
#define GAT_ALPHA 0.2f
#define MSHIFT 20.0f          // safe upper bound on max_j e2[j] (pre-scale)
#define LOG2E 1.44269504f

#define JSPLIT 16             // grid = 128 row-groups x 16 = 2048 blocks
#define JSHIFT 4
#define JW (NN / JSPLIT)      // 512 j per block
#define KSTEPS (JW / 32)      // 16 k-steps of 32

#define HTS 520               // hs row stride (bf16): 260 dwords, %32=4 -> 2-way (free)

#define EXP2F(x) __builtin_amdgcn_exp2f(x)

typedef __attribute__((ext_vector_type(8))) __bf16 bf16x8;
typedef __attribute__((ext_vector_type(4))) float f32x4;
typedef __attribute__((ext_vector_type(4))) int i32x4;

// RNE fp32->bf16 pair pack, pure bit ops. Returns (bf16(hi)<<16)|bf16(lo).
__device__ __forceinline__ unsigned pack_bf16_rne(float hi, float lo) {
    unsigned uh = __float_as_uint(hi);
    unsigned ul = __float_as_uint(lo);
    uh = uh + 0x7FFFu + ((uh >> 16) & 1u);
    ul = ul + 0x7FFFu + ((ul >> 16) & 1u);
    return (uh & 0xFFFF0000u) | (ul >> 16);
}

// ---------------------------------------------------------------------------
// Kernel A: h = x@W (fp32), e1/e2 = (h@a1, h@a2) * log2(e),
//           ht = h^T bf16 [64][8192]. 256 blocks x 256 thr, 32 rows/block.
// (unchanged — proven)
// ---------------------------------------------------------------------------
__global__ __launch_bounds__(256) void gat_linear(
    const float* __restrict__ x, const float* __restrict__ W,
    const float* __restrict__ av, __hip_bfloat16* __restrict__ ht,
    float* __restrict__ e1, float* __restrict__ e2)
{
    __shared__ float xs[32][33];
    __shared__ float Ws[32][64];
    __shared__ float ep[2][32][17];

    const int t  = threadIdx.x;
    const int fq = t & 15;
    const int rq = t >> 4;
    const int i0 = blockIdx.x * 32;

    const int kl = t & 31, r0 = t >> 5;
    const int fw = t & 63, kq = t >> 6;

    float acc[2][4] = {};

    for (int kt = 0; kt < KF; kt += 32) {
        #pragma unroll
        for (int m = 0; m < 4; ++m)
            xs[kl][r0 + 8 * m] = x[(size_t)(i0 + r0 + 8 * m) * KF + kt + kl];
        #pragma unroll
        for (int m = 0; m < 8; ++m)
            Ws[kq + 4 * m][fw] = W[(size_t)(kt + kq + 4 * m) * FF + fw];
        __syncthreads();
        #pragma unroll
        for (int kk = 0; kk < 32; ++kk) {
            float x0 = xs[kk][rq * 2];
            float x1 = xs[kk][rq * 2 + 1];
            f32x4 wv = *(const f32x4*)&Ws[kk][fq * 4];
            #pragma unroll
            for (int v = 0; v < 4; ++v) {
                acc[0][v] += x0 * wv[v];
                acc[1][v] += x1 * wv[v];
            }
        }
        __syncthreads();
    }

    #pragma unroll
    for (int v = 0; v < 4; ++v) {
        int f = fq * 4 + v;
        unsigned w = pack_bf16_rne(acc[1][v], acc[0][v]);
        *(unsigned*)&ht[(size_t)f * NN + i0 + rq * 2] = w;
    }

    f32x4 a1v = *(const f32x4*)&av[fq * 4];
    f32x4 a2v = *(const f32x4*)&av[64 + fq * 4];
    #pragma unroll
    for (int u = 0; u < 2; ++u) {
        float s1 = 0.f, s2 = 0.f;
        #pragma unroll
        for (int v = 0; v < 4; ++v) {
            s1 += acc[u][v] * a1v[v];
            s2 += acc[u][v] * a2v[v];
        }
        ep[0][rq * 2 + u][fq] = s1;
        ep[1][rq * 2 + u][fq] = s2;
    }
    __syncthreads();
    if (t < 32) {
        float s1 = 0.f, s2 = 0.f;
        #pragma unroll
        for (int q = 0; q < 16; ++q) { s1 += ep[0][t][q]; s2 += ep[1][t][q]; }
        e1[i0 + t] = s1 * LOG2E;
        e2[i0 + t] = s2 * LOG2E;
    }
}

// ---------------------------------------------------------------------------
// Kernel B: barrier-free adj stream. Block = 64 rows x 512 j, 4 waves.
// ht slice (64KB) + e2 slice (2KB) staged in LDS once (one barrier).
// adj is read DIRECTLY in the consumer lane mapping: lane (n16,quad) loads
// adj[row][j0+st*32+quad*8..+7] as 2x dwordx4; a wave's 8-instruction group
// consumes every byte of the touched lines exactly once (same HBM efficiency
// as staged). Latency (R2's failure mode) is covered by SUBTILE-depth
// register double-buffering: 8x int4 (one 4-step subtile) issued a full
// subtile (~0.5us of VALU+MFMA) before first use. No msk LDS, no pack
// VALU, no in-loop barriers: the 268MB stream issues continuously,
// throttled only by vmcnt back-pressure (pure BW-bound).
// __launch_bounds__(256,2): LDS caps at 2 blocks/CU anyway; allow ~256 VGPR.
// ---------------------------------------------------------------------------
__global__ __launch_bounds__(256, 2) void gat_attn(
    const int* __restrict__ adj, const __hip_bfloat16* __restrict__ ht,
    const float* __restrict__ e1, const float* __restrict__ e2,
    float* __restrict__ accs, float* __restrict__ lsums)
{
    __shared__ __hip_bfloat16 hs[64 * HTS];            // 66560 B
    __shared__ float e2s[JW];                          // 2048 B

    const int t     = threadIdx.x;
    const int lane  = t & 63;
    const int wv    = t >> 6;
    const int n16   = lane & 15;
    const int quad  = lane >> 4;
    const int split = blockIdx.x & (JSPLIT - 1);
    const int i0    = (blockIdx.x >> JSHIFT) * 64 + wv * 16;  // wave row base
    const int j0    = split * JW;
    const int row   = i0 + n16;                               // global row

    // ---- stage ht slice: [64][512] bf16, coalesced ----
    #pragma unroll
    for (int k = 0; k < 16; ++k) {
        int g  = t + k * 256;          // 4096 chunks of 8 bf16
        int f  = g >> 6;
        int jl = (g & 63) * 8;
        *(bf16x8*)&hs[f * HTS + jl] =
            *(const bf16x8*)&ht[(size_t)f * NN + j0 + jl];
    }
    // ---- stage e2 slice ----
    if (t < JW / 4)
        *(float4*)&e2s[t * 4] = *(const float4*)&e2[j0 + t * 4];

    // ---- adj: per-lane direct, subtile register pipeline ----
    const int* __restrict__ apL = adj + (size_t)row * NN + j0 + quad * 8;
    i32x4 bufA[8], bufB[8];

#define ISSUE(BUF, stb)                                                        \
    BUF[0] = *(const i32x4*)(apL + (stb) * 128 + 0);                           \
    BUF[1] = *(const i32x4*)(apL + (stb) * 128 + 4);                           \
    BUF[2] = *(const i32x4*)(apL + (stb) * 128 + 32);                          \
    BUF[3] = *(const i32x4*)(apL + (stb) * 128 + 36);                          \
    BUF[4] = *(const i32x4*)(apL + (stb) * 128 + 64);                          \
    BUF[5] = *(const i32x4*)(apL + (stb) * 128 + 68);                          \
    BUF[6] = *(const i32x4*)(apL + (stb) * 128 + 96);                          \
    BUF[7] = *(const i32x4*)(apL + (stb) * 128 + 100);

    ISSUE(bufA, 0)
    ISSUE(bufB, 1)

    __syncthreads();

    const float e1L = e1[row];
    float ms = e1L + MSHIFT * LOG2E;
    const float miL = ms > 0.f ? ms : GAT_ALPHA * ms;
    const float c0  = e1L - miL;                 // t0 = e2 + c0
    const float c1  = GAT_ALPHA * e1L - miL;     // t1 = fma(alpha, e2, c1)

    const __hip_bfloat16* hp = hs + n16 * HTS + quad * 8;  // B rows n16,+16,+32,+48
    const float* ep0 = e2s + quad * 8;

    f32x4 dacc0 = {0.f,0.f,0.f,0.f}, dacc1 = {0.f,0.f,0.f,0.f};
    f32x4 dacc2 = {0.f,0.f,0.f,0.f}, dacc3 = {0.f,0.f,0.f,0.f};
    f32x4 dl    = {0.f,0.f,0.f,0.f};

    const i32x4 ones_i = {0x3F803F80, 0x3F803F80, 0x3F803F80, 0x3F803F80};
    const bf16x8 ones  = __builtin_bit_cast(bf16x8, ones_i);

    // prefetch step 0 of e2/b fragments (LDS)
    f32x4  e0 = *(const f32x4*)(ep0);
    f32x4  ev = *(const f32x4*)(ep0 + 4);
    bf16x8 b0 = *(const bf16x8*)(hp);
    bf16x8 b1 = *(const bf16x8*)(hp + 16 * HTS);
    bf16x8 b2 = *(const bf16x8*)(hp + 32 * HTS);
    bf16x8 b3 = *(const bf16x8*)(hp + 48 * HTS);

#define PJ(eval, an)                                                           \
        ( (an) > 0                                                             \
            ? EXP2F(fmaxf(c0 + (eval), __builtin_fmaf(GAT_ALPHA, (eval), c1))) \
            : 0.f )

#define STEP(stg, AX0, AX1)                                                    \
    {                                                                          \
        const f32x4  ce0 = e0, cev = ev;                                       \
        const bf16x8 cb0 = b0, cb1 = b1, cb2 = b2, cb3 = b3;                   \
        if ((stg) + 1 < KSTEPS) {                                              \
            e0 = *(const f32x4*)(ep0 + ((stg) + 1) * 32);                      \
            ev = *(const f32x4*)(ep0 + ((stg) + 1) * 32 + 4);                  \
            b0 = *(const bf16x8*)(hp + ((stg) + 1) * 32);                      \
            b1 = *(const bf16x8*)(hp + 16 * HTS + ((stg) + 1) * 32);           \
            b2 = *(const bf16x8*)(hp + 32 * HTS + ((stg) + 1) * 32);           \
            b3 = *(const bf16x8*)(hp + 48 * HTS + ((stg) + 1) * 32);           \
        }                                                                      \
        float p0 = PJ(ce0.x, (AX0).x);                                         \
        float p1 = PJ(ce0.y, (AX0).y);                                         \
        float p2 = PJ(ce0.z, (AX0).z);                                         \
        float p3 = PJ(ce0.w, (AX0).w);                                         \
        float p4 = PJ(cev.x, (AX1).x);                                         \
        float p5 = PJ(cev.y, (AX1).y);                                         \
        float p6 = PJ(cev.z, (AX1).z);                                         \
        float p7 = PJ(cev.w, (AX1).w);                                         \
        i32x4 iv;                                                              \
        iv.x = (int)pack_bf16_rne(p1, p0);                                     \
        iv.y = (int)pack_bf16_rne(p3, p2);                                     \
        iv.z = (int)pack_bf16_rne(p5, p4);                                     \
        iv.w = (int)pack_bf16_rne(p7, p6);                                     \
        bf16x8 af = __builtin_bit_cast(bf16x8, iv);                            \
        dacc0 = __builtin_amdgcn_mfma_f32_16x16x32_bf16(af, cb0, dacc0, 0,0,0);\
        dacc1 = __builtin_amdgcn_mfma_f32_16x16x32_bf16(af, cb1, dacc1, 0,0,0);\
        dacc2 = __builtin_amdgcn_mfma_f32_16x16x32_bf16(af, cb2, dacc2, 0,0,0);\
        dacc3 = __builtin_amdgcn_mfma_f32_16x16x32_bf16(af, cb3, dacc3, 0,0,0);\
        dl    = __builtin_amdgcn_mfma_f32_16x16x32_bf16(af, ones, dl,   0,0,0);\
    }

    // subtile 0 from bufA, then refill bufA with subtile 2
    STEP( 0, bufA[0], bufA[1])
    STEP( 1, bufA[2], bufA[3])
    STEP( 2, bufA[4], bufA[5])
    STEP( 3, bufA[6], bufA[7])
    ISSUE(bufA, 2)
    // subtile 1 from bufB, refill bufB with subtile 3
    STEP( 4, bufB[0], bufB[1])
    STEP( 5, bufB[2], bufB[3])
    STEP( 6, bufB[4], bufB[5])
    STEP( 7, bufB[6], bufB[7])
    ISSUE(bufB, 3)
    // subtile 2 from bufA
    STEP( 8, bufA[0], bufA[1])
    STEP( 9, bufA[2], bufA[3])
    STEP(10, bufA[4], bufA[5])
    STEP(11, bufA[6], bufA[7])
    // subtile 3 from bufB
    STEP(12, bufB[0], bufB[1])
    STEP(13, bufB[2], bufB[3])
    STEP(14, bufB[4], bufB[5])
    STEP(15, bufB[6], bufB[7])

#undef STEP
#undef PJ
#undef ISSUE

    // dl D-tile: every column holds the row-sum; lanes n16==0 cover all 16 rows
    if (n16 == 0) {
        lsums[(size_t)split * NN + i0 + quad * 4 + 0] = dl.x;
        lsums[(size_t)split * NN + i0 + quad * 4 + 1] = dl.y;
        lsums[(size_t)split * NN + i0 + quad * 4 + 2] = dl.z;
        lsums[(size_t)split * NN + i0 + quad * 4 + 3] = dl.w;
    }

    // D layout: col = lane&15 (feature), row = quad*4 + reg (m89-verified)
    float* ab = accs + (size_t)split * NN * FF + (size_t)(i0 + quad * 4) * FF + n16;
#define STORE4(dv, ftofs)                                                      \
    ab[0 * FF + (ftofs)] = (dv).x;                                             \
    ab[1 * FF + (ftofs)] = (dv).y;                                             \
    ab[2 * FF + (ftofs)] = (dv).z;                                             \
    ab[3 * FF + (ftofs)] = (dv).w;
    STORE4(dacc0, 0)
    STORE4(dacc1, 16)
    STORE4(dacc2, 32)
    STORE4(dacc3, 48)
#undef STORE4
}

// ---------------------------------------------------------------------------
// Epilogue: out = elu( (sum_s accs[s]) / (sum_s lsums[s]) )
// ---------------------------------------------------------------------------
__global__ __launch_bounds__(256) void gat_epilogue(
    const float* __restrict__ accs, const float* __restrict__ lsums,
    float* __restrict__ out)
{
    const int idx = (blockIdx.x * 256 + threadIdx.x) * 4;  // 4 consecutive f, same row
    const int row = idx >> 6;

    float l = 0.f;
    #pragma unroll
    for (int s = 0; s < JSPLIT; ++s) l += lsums[(size_t)s * NN + row];

    f32x4 a = {0.f, 0.f, 0.f, 0.f};
    #pragma unroll
    for (int s = 0; s < JSPLIT; ++s) {
        f32x4 v = *(const f32x4*)(accs + (size_t)s * NN * FF + idx);
        a.x += v.x; a.y += v.y; a.z += v.z; a.w += v.w;
    }

    const float li = 1.f / l;
    f32x4 o;
    o.x = a.x * li; o.y = a.y * li; o.z = a.z * li; o.w = a.w * li;
    o.x = o.x > 0.f ? o.x : __expf(o.x) - 1.f;
    o.y = o.y > 0.f ? o.y : __expf(o.y) - 1.f;
    o.z = o.z > 0.f ? o.z : __expf(o.z) - 1.f;
    o.w = o.w > 0.f ? o.w : __expf(o.w) - 1.f;
    *(f32x4*)(out + idx) = o;
}

extern "C" void kernel_launch(void* const* d_in, const int* in_sizes, int n_in,
                              void* d_out, int out_size, void* d_ws, size_t ws_size,
                              hipStream_t stream) {
    const float* x   = (const float*)d_in[0];
    const int*   adj = (const int*)d_in[1];
    const float* W   = (const float*)d_in[2];
    const float* av  = (const float*)d_in[3];
    float* out = (float*)d_out;

    // ws: ht bf16[64*8192] (1MB) | e1 f32[8192] | e2 f32[8192]
    //     | accs f32[16][8192*64] (32MB) | lsums f32[16][8192] (512KB)
    char* wsb = (char*)d_ws;
    __hip_bfloat16* ht = (__hip_bfloat16*)wsb;
    float* e1    = (float*)(wsb + (1 << 20));
    float* e2    = e1 + NN;
    float* accs  = e2 + NN;
    float* lsums = accs + (size_t)JSPLIT * NN * FF;

    gat_linear<<<256, 256, 0, stream>>>(x, W, av, ht, e1, e2);
    gat_attn<<<(NN / 64) * JSPLIT, 256, 0, stream>>>(adj, ht, e1, e2, accs, lsums);
    gat_epilogue<<<NN * FF / 1024, 256, 0, stream>>>(accs, lsums, out);
}